// Round 10
// baseline (89.972 us; speedup 1.0000x reference)
//
#include <hip/hip_runtime.h>

// Chamfer distance, B=16, N=M=4096, 2-D fp32 points, prefix-length masks.
// d_out: [fwd 16*4096][bwd 16*4096] fp32.
//
// R10: R9 falsified the spill theory (named scalars == arrays). Revised
// model: v_pk_fma_f32 is HALF-RATE on CDNA4 (157 TF fp32 peak already counts
// packed), so R6's loop costs 10 cyc per 2 points per query - main floor
// ~14 us, matching all measurements. Only lever left: v_dot2_f32_f16
// (full-rate VOP3P, f16 products + f32 accumulate): per point per query
// 1 dot2 (acc = t2, adds -2q.t) + 1/2 min3 => 3 cyc/pair vs 10.
// R4's apparent dot2 failure is re-attributed to its VGPR=48 spill.
// LDS record: {bits(h2 xy), f32 t2} x2 per float4 (16B / 2 points); tail
// masked by t2 = 1e30 poison. Consistent f16 rounding (s2, t2 computed from
// ROUNDED coords) => computed value is exactly |q_h - t_h|^2 + O(f32);
// absmax ~7.8e-3 (R3-measured), threshold 3.2e-2.
// Structure = R6 (best, 84.06): compacted (row, 128-pt chunk) blocks,
// (256,2) no-spill, plain partial stores, separate reduce. Zero atomics.

#define NQ 16
typedef _Float16 h2 __attribute__((ext_vector_type(2)));

#if defined(__has_builtin)
#  if __has_builtin(__builtin_amdgcn_fdot2)
#    define FDOT2(a, b, c) __builtin_amdgcn_fdot2((a), (b), (c), false)
#  endif
#endif
#ifndef FDOT2  // correct-but-slower fallback
#  define FDOT2(a, b, c) fmaf((float)(a)[0], (float)(b)[0], fmaf((float)(a)[1], (float)(b)[1], (c)))
#endif

__global__ __launch_bounds__(256, 2) void chamfer_main(
    const float* __restrict__ src, const float* __restrict__ tgt,
    const int* __restrict__ slen, const int* __restrict__ tlen,
    float* __restrict__ part)   // [32 rows][32 slices][4096] partial mins
{
    __shared__ float4 sh[64];   // {bits(h2 p0), n0, bits(h2 p1), n1} per pair

    const int g   = blockIdx.x;
    const int tid = threadIdx.x;

    // Compacted work lookup: g -> (row, pc). Uniform SALU.
    int row = -1, pc = 0, Lp = 0, acc = 0;
    #pragma unroll
    for (int rr = 0; rr < 32; ++rr) {
        const int L = (rr < 16) ? tlen[rr] : slen[rr - 16];  // search-side length
        const int n = (L + 127) >> 7;                        // active 128-pt chunks
        if (row < 0 && g < acc + n) { row = rr; pc = g - acc; Lp = L; }
        acc += n;
    }
    if (row < 0) return;             // beyond total active units
    const int dir = row >> 4, b = row & 15;

    const float* Q = dir ? tgt : src;
    const float* P = dir ? src : tgt;

    // Stage 128 points (64 pairs): f16-rounded coords + f32 t2 from ROUNDED
    // coords; tail poisoned via n = 1e30 (always loses; active chunk has
    // >= 1 valid point so the real min survives).
    if (tid < 64) {
        const int base = pc * 128 + tid * 2;
        const float4 pp = ((const float4*)P)[(b * 4096 + base) >> 1];  // {x0,y0,x1,y1}
        const h2 t0 = h2{(_Float16)pp.x, (_Float16)pp.y};
        const h2 t1 = h2{(_Float16)pp.z, (_Float16)pp.w};
        const float t0x = (float)t0[0], t0y = (float)t0[1];
        const float t1x = (float)t1[0], t1y = (float)t1[1];
        const float n0 = (base + 0 < Lp) ? fmaf(t0x, t0x, t0y * t0y) : 1e30f;
        const float n1 = (base + 1 < Lp) ? fmaf(t1x, t1x, t1y * t1y) : 1e30f;
        sh[tid] = make_float4(__builtin_bit_cast(float, t0), n0,
                              __builtin_bit_cast(float, t1), n1);
    }
    __syncthreads();

    // 16 queries/thread (whole 4096-query row), consistently f16-rounded.
    h2 qh[NQ]; float s2[NQ], best[NQ];
    #pragma unroll
    for (int k = 0; k < NQ; ++k) {
        const float2 q = ((const float2*)Q)[b * 4096 + tid + k * 256];
        const _Float16 qx = (_Float16)q.x, qy = (_Float16)q.y;
        const float qxf = (float)qx, qyf = (float)qy;
        s2[k]   = fmaf(qxf, qxf, qyf * qyf);
        qh[k]   = h2{(_Float16)(-2.0f * qxf), (_Float16)(-2.0f * qyf)};  // exact x2
        best[k] = 3.0e38f;
    }

    // Per j (2 points): 1 ds_read_b128 + 16q x (2 v_dot2_f32_f16 + 1 min3).
    #pragma unroll 4
    for (int j = 0; j < 64; ++j) {
        const float4 td = sh[j];
        const h2 th0 = __builtin_bit_cast(h2, td.x);
        const h2 th1 = __builtin_bit_cast(h2, td.z);
        #pragma unroll
        for (int k = 0; k < NQ; ++k) {
            const float v0 = FDOT2(qh[k], th0, td.y);   // t2 - 2*q.t (f32 acc)
            const float v1 = FDOT2(qh[k], th1, td.w);
            best[k] = fminf(best[k], fminf(v0, v1));    // v_min3_f32
        }
    }

    // Plain coalesced stores to this unit's private slice. No atomics.
    float* slice = part + ((size_t)row * 32 + pc) * 4096;
    #pragma unroll
    for (int k = 0; k < NQ; ++k)
        slice[tid + k * 256] = fmaxf(best[k] + s2[k], 0.f);  // clamp commutes with min
}

__global__ __launch_bounds__(128) void chamfer_reduce(
    const float* __restrict__ part,
    const int* __restrict__ slen, const int* __restrict__ tlen,
    float* __restrict__ out)
{
    const int t  = blockIdx.x * 128 + threadIdx.x;   // 32768 threads, 4 elems each
    const int i4 = t * 4;
    const int row = i4 >> 12;                        // dir*16 + b
    const int dir = row >> 4, b = row & 15;
    const int i   = i4 & 4095;
    const int Lq = dir ? tlen[b] : slen[b];
    const int Lp = dir ? slen[b] : tlen[b];
    const int nact = (Lp + 127) >> 7;                // active slices (block-uniform)

    float4 best = make_float4(1e10f, 1e10f, 1e10f, 1e10f);
    const float4* p = (const float4*)(part + (size_t)row * 32 * 4096 + i);
    #pragma unroll 4
    for (int s = 0; s < nact; ++s) {
        const float4 v = p[(size_t)s * 1024];        // stride 4096 floats
        best.x = fminf(best.x, v.x);
        best.y = fminf(best.y, v.y);
        best.z = fminf(best.z, v.z);
        best.w = fminf(best.w, v.w);
    }
    float4 r;
    r.x = (i + 0 < Lq) ? sqrtf(best.x) : 0.f;        // nact==0 -> sqrt(1e10), matches ref
    r.y = (i + 1 < Lq) ? sqrtf(best.y) : 0.f;
    r.z = (i + 2 < Lq) ? sqrtf(best.z) : 0.f;
    r.w = (i + 3 < Lq) ? sqrtf(best.w) : 0.f;
    ((float4*)out)[t] = r;
}

extern "C" void kernel_launch(void* const* d_in, const int* in_sizes, int n_in,
                              void* d_out, int out_size, void* d_ws, size_t ws_size,
                              hipStream_t stream) {
    const float* src = (const float*)d_in[0];   // [16,4096,2] f32
    const float* tgt = (const float*)d_in[1];   // [16,4096,2] f32
    const int* slen  = (const int*)d_in[2];     // [16] i32
    const int* tlen  = (const int*)d_in[3];     // [16] i32
    float* part = (float*)d_ws;                 // 32 x 32 x 4096 f32 = 16.8 MB

    chamfer_main<<<1024, 256, 0, stream>>>(src, tgt, slen, tlen, part);
    chamfer_reduce<<<256, 128, 0, stream>>>(part, slen, tlen, (float*)d_out);
}

// Round 11
// 84.108 us; speedup vs baseline: 1.0697x; 1.0697x over previous
//
#include <hip/hip_runtime.h>

// Chamfer distance, B=16, N=M=4096, 2-D fp32 points, prefix-length masks.
// d_out: [fwd 16*4096][bwd 16*4096] fp32.
//
// R11: R6/R7/R9/R10 (four different inner loops, 48-52 instrs/j) all land at
// main ~27+-3us while VALU-busy back-solves to ~10us => main is STALL-bound
// at 2 waves/SIMD (launch_bounds(256,2), ~528 active blocks = 2.06/CU), not
// issue-bound. This round doubles TLP at fixed work and fixed traffic:
//   NQ 16 -> 8 (block covers a 2048-query half) => ~1056 active blocks
//   (~4.1/CU), launch_bounds(256,4), ~90 VGPR => 4 waves/SIMD.
// Partial traffic unchanged (each chunk still emits 4096 partials).
// Inner loop: proven f32 path, 2 v_pk_fma_f32 + 1 v_min3_f32 per point-pair
// per query; |t|^2 rebuilt per j (2 pk, amortized over 8 queries).
// Masking: poisoned coords (1e15) for tail; compacted (chunk, qhalf) blocks;
// plain partial stores + separate reduce; zero atomics/fences (R3 lesson).

#define NQ 8
typedef float f2 __attribute__((ext_vector_type(2)));

__global__ __launch_bounds__(256, 4) void chamfer_main(
    const float* __restrict__ src, const float* __restrict__ tgt,
    const int* __restrict__ slen, const int* __restrict__ tlen,
    float* __restrict__ part)   // [32 rows][32 slices][4096] partial mins
{
    __shared__ float4 sh_xy[64];   // {x0,x1,y0,y1} per point-pair (16 B/pair)

    const int g     = blockIdx.x;
    const int u     = g >> 1;        // active (row, chunk) unit
    const int qhalf = g & 1;         // which 2048-query half
    const int tid   = threadIdx.x;

    // Compacted work lookup: u -> (row, pc). Uniform SALU.
    int row = -1, pc = 0, Lp = 0, acc = 0;
    #pragma unroll
    for (int rr = 0; rr < 32; ++rr) {
        const int L = (rr < 16) ? tlen[rr] : slen[rr - 16];  // search-side length
        const int n = (L + 127) >> 7;                        // active 128-pt chunks
        if (row < 0 && u < acc + n) { row = rr; pc = u - acc; Lp = L; }
        acc += n;
    }
    if (row < 0) return;             // beyond total active units
    const int dir = row >> 4, b = row & 15;

    const float* Q = dir ? tgt : src;
    const float* P = dir ? src : tgt;

    // Stage 128 points (64 pairs), pair-packed; POISON COORDS for idx >= Lp
    // (1e15^2 dominates any real d2; every active chunk has >=1 valid point).
    if (tid < 64) {
        const int base = pc * 128 + tid * 2;
        const float4 pp = ((const float4*)P)[(b * 4096 + base) >> 1];  // {x0,y0,x1,y1}
        const float x0 = (base + 0 < Lp) ? pp.x : 1e15f;
        const float y0 = (base + 0 < Lp) ? pp.y : 1e15f;
        const float x1 = (base + 1 < Lp) ? pp.z : 1e15f;
        const float y1 = (base + 1 < Lp) ? pp.w : 1e15f;
        sh_xy[tid] = make_float4(x0, x1, y0, y1);            // {x0,x1,y0,y1}
    }
    __syncthreads();

    // 8 queries/thread (2048-query half). Splatted -2q for packed fma.
    const int qbase = b * 4096 + qhalf * 2048 + tid;
    f2 mx2[NQ], my2[NQ];
    float s2[NQ], best[NQ];
    #pragma unroll
    for (int k = 0; k < NQ; ++k) {
        const float2 q = ((const float2*)Q)[qbase + k * 256];
        const float mx = -2.f * q.x, my = -2.f * q.y;
        mx2[k] = f2{mx, mx};
        my2[k] = f2{my, my};
        s2[k]  = fmaf(q.x, q.x, q.y * q.y);
        best[k] = 3.0e38f;
    }

    // Per point-pair per query: 2 v_pk_fma_f32 + 1 v_min3_f32.
    #pragma unroll 4
    for (int j = 0; j < 64; ++j) {
        const float4 xy = sh_xy[j];
        const f2 xp = f2{xy.x, xy.y};
        const f2 yp = f2{xy.z, xy.w};
        const f2 np = __builtin_elementwise_fma(xp, xp, yp * yp);
        #pragma unroll
        for (int k = 0; k < NQ; ++k) {
            f2 v = __builtin_elementwise_fma(xp, mx2[k], np);  // n - 2qx*tx
            v = __builtin_elementwise_fma(yp, my2[k], v);      // n - 2q.t
            best[k] = fminf(best[k], fminf(v.x, v.y));         // v_min3_f32
        }
    }

    // Plain coalesced stores to this unit's private slice half. No atomics.
    float* slice = part + ((size_t)row * 32 + pc) * 4096 + qhalf * 2048;
    #pragma unroll
    for (int k = 0; k < NQ; ++k)
        slice[tid + k * 256] = fmaxf(best[k] + s2[k], 0.f);  // clamp commutes with min
}

__global__ __launch_bounds__(128) void chamfer_reduce(
    const float* __restrict__ part,
    const int* __restrict__ slen, const int* __restrict__ tlen,
    float* __restrict__ out)
{
    const int t  = blockIdx.x * 128 + threadIdx.x;   // 32768 threads, 4 elems each
    const int i4 = t * 4;
    const int row = i4 >> 12;                        // dir*16 + b
    const int dir = row >> 4, b = row & 15;
    const int i   = i4 & 4095;
    const int Lq = dir ? tlen[b] : slen[b];
    const int Lp = dir ? slen[b] : tlen[b];
    const int nact = (Lp + 127) >> 7;                // active slices (block-uniform)

    float4 best = make_float4(1e10f, 1e10f, 1e10f, 1e10f);
    const float4* p = (const float4*)(part + (size_t)row * 32 * 4096 + i);
    #pragma unroll 4
    for (int s = 0; s < nact; ++s) {
        const float4 v = p[(size_t)s * 1024];        // stride 4096 floats
        best.x = fminf(best.x, v.x);
        best.y = fminf(best.y, v.y);
        best.z = fminf(best.z, v.z);
        best.w = fminf(best.w, v.w);
    }
    float4 r;
    r.x = (i + 0 < Lq) ? sqrtf(best.x) : 0.f;        // nact==0 -> sqrt(1e10), matches ref
    r.y = (i + 1 < Lq) ? sqrtf(best.y) : 0.f;
    r.z = (i + 2 < Lq) ? sqrtf(best.z) : 0.f;
    r.w = (i + 3 < Lq) ? sqrtf(best.w) : 0.f;
    ((float4*)out)[t] = r;
}

extern "C" void kernel_launch(void* const* d_in, const int* in_sizes, int n_in,
                              void* d_out, int out_size, void* d_ws, size_t ws_size,
                              hipStream_t stream) {
    const float* src = (const float*)d_in[0];   // [16,4096,2] f32
    const float* tgt = (const float*)d_in[1];   // [16,4096,2] f32
    const int* slen  = (const int*)d_in[2];     // [16] i32
    const int* tlen  = (const int*)d_in[3];     // [16] i32
    float* part = (float*)d_ws;                 // 32 x 32 x 4096 f32 = 16.8 MB

    chamfer_main<<<2048, 256, 0, stream>>>(src, tgt, slen, tlen, part);
    chamfer_reduce<<<256, 128, 0, stream>>>(part, slen, tlen, (float*)d_out);
}